// Round 8
// baseline (379.639 us; speedup 1.0000x reference)
//
#include <hip/hip_runtime.h>
#include <math.h>

#pragma clang fp contract(off)

#define QN   512   // queries per image
#define NN   768   // total targets (bs*T)
#define BSZ  32    // batch
#define TPI  24    // targets per image
#define NCLS 92    // classes
#define SROWS 64   // softmax rows per block
#define GRID 768

// single-wave LDS fence: order this wave's ds_writes before its ds_reads
#define WFENCE() asm volatile("s_waitcnt lgkmcnt(0)" ::: "memory")

// ---------- XLA-faithful special functions (verified bit-exact, round 2) ----------

__device__ __forceinline__ float xla_erf_f32(float x) {
#pragma clang fp contract(off)
  float x2 = x * x;
  float p = -2.72614225801306e-10f;
  p = fmaf(x2, p, 2.77068142495902e-08f);
  p = fmaf(x2, p, -2.10102402082508e-06f);
  p = fmaf(x2, p, -5.69250639462346e-05f);
  p = fmaf(x2, p, -7.34990630326855e-04f);
  p = fmaf(x2, p, -2.95459980854025e-03f);
  p = fmaf(x2, p, -1.60960333262415e-02f);
  p = x * p;
  float q = -1.45660718464996e-05f;
  q = fmaf(x2, q, -2.13374055278905e-04f);
  q = fmaf(x2, q, -1.68282697438203e-03f);
  q = fmaf(x2, q, -7.37332916720468e-03f);
  q = fmaf(x2, q, -1.42647390514189e-02f);
  float r = p / q;
  if (fabsf(x) >= 3.832506856900711f) r = copysignf(1.0f, x);
  return r;
}

__device__ __forceinline__ float xla_erfinv_f32(float b) {
#pragma clang fp contract(off)
  float bb = b * b;
  float u = (-bb) + 1.0f;
  float w = -((float)log((double)u));
  float p;
  if (w < 5.0f) {
    float ww = w - 2.5f;
    p = 2.81022636e-08f;
    p = p * ww + 3.43273939e-07f;
    p = p * ww - 3.5233877e-06f;
    p = p * ww - 4.39150654e-06f;
    p = p * ww + 0.00021858087f;
    p = p * ww - 0.00125372503f;
    p = p * ww - 0.00417768164f;
    p = p * ww + 0.246640727f;
    p = p * ww + 1.50140941f;
  } else {
    float ww = (float)sqrt((double)w) - 3.0f;
    p = -0.000200214257f;
    p = p * ww + 0.000100950558f;
    p = p * ww + 0.00134934322f;
    p = p * ww - 0.00367342844f;
    p = p * ww + 0.00573950773f;
    p = p * ww - 0.0076224613f;
    p = p * ww + 0.00943887047f;
    p = p * ww + 1.00167406f;
    p = p * ww + 2.83297682f;
  }
  return p * b;
}

// ---------- fx element (identical algebra to validated k_build) ----------

__device__ __forceinline__ float build_fx(const float* __restrict__ logits,
                                          const float* __restrict__ pboxes,
                                          const float* __restrict__ mx,
                                          const float* __restrict__ sm,
                                          float4 tb, int lab, int r) {
#pragma clang fp contract(off)
  float pc = expf(logits[(size_t)r * NCLS + lab] - mx[r]) / sm[r];
  float cost_class = -pc;

  float4 pb = ((const float4*)pboxes)[r];

  float cost_bbox = ((fabsf(pb.x - tb.x) + fabsf(pb.y - tb.y)) +
                     fabsf(pb.z - tb.z)) + fabsf(pb.w - tb.w);

  float p0 = pb.x - 0.5f * pb.z;
  float p1 = pb.y - 0.5f * pb.w;
  float p2 = pb.x + 0.5f * pb.z;
  float p3 = pb.y + 0.5f * pb.w;
  float t0 = tb.x - 0.5f * tb.z;
  float t1 = tb.y - 0.5f * tb.w;
  float t2 = tb.x + 0.5f * tb.z;
  float t3 = tb.y + 0.5f * tb.w;

  float area1 = (p2 - p0) * (p3 - p1);
  float area2 = (t2 - t0) * (t3 - t1);
  float ltx = fmaxf(p0, t0), lty = fmaxf(p1, t1);
  float rbx = fminf(p2, t2), rby = fminf(p3, t3);
  float whx = fmaxf(rbx - ltx, 0.0f), why = fmaxf(rby - lty, 0.0f);
  float inter = whx * why;
  float uni = (area1 + area2) - inter;
  float iou = inter / uni;
  float l2x = fminf(p0, t0), l2y = fminf(p1, t1);
  float r2x = fmaxf(p2, t2), r2y = fmaxf(p3, t3);
  float w2x = fmaxf(r2x - l2x, 0.0f), w2y = fmaxf(r2y - l2y, 0.0f);
  float area = w2x * w2y;
  float giou = iou - (area - uni) / area;

  float C = (cost_bbox + cost_class) + (-giou);

  float z = (-C + 5.5f) / 3.5355339059327378f;
  float prob = 0.5f * (1.0f + xla_erf_f32(z));
  return 0.4242640687119285f * xla_erfinv_f32(prob);
}

// ---------- scan helpers (validated rounds 3-7) ----------

__device__ __forceinline__ void wave_maxcount(const float* arr, int lane, float bound,
                                              float& mxv, int& cnt) {
  float m = -INFINITY; int c = 0;
#pragma unroll
  for (int k = 0; k < QN / 64; ++k) {
    float v = fminf(arr[lane + 64 * k], 100.0f);
    if (v < bound) {
      if (v > m) { m = v; c = 1; }
      else if (v == m) c++;
    }
  }
  for (int off = 32; off > 0; off >>= 1) {
    float om = __shfl_xor(m, off);
    int oc = __shfl_xor(c, off);
    if (om > m) { m = om; c = oc; }
    else if (om == m) c += oc;
  }
  mxv = m; cnt = c;
}

__device__ __forceinline__ int wave_argmax(const float* arr, int lane) {
  float bv = -INFINITY; int bi = 0x7fffffff;
#pragma unroll
  for (int k = 0; k < QN / 64; ++k) {
    float v = arr[lane + 64 * k];
    if (v > bv) { bv = v; bi = lane + 64 * k; }
  }
  for (int off = 32; off > 0; off >>= 1) {
    float ov = __shfl_xor(bv, off);
    int oi = __shfl_xor(bi, off);
    if (ov > bv || (ov == bv && oi < bi)) { bv = ov; bi = oi; }
  }
  return bi;
}

__device__ __forceinline__ bool ms_update(float x, float& a1, int& c1, float& a2, int& c2) {
  x = fminf(x, 100.0f);
  bool rescan = false;
  if (x == a1) {
    if (--c1 == 0) rescan = true;
  } else if (x == a2) {
    if (--c2 == 0) rescan = true;
  }
  if (!rescan) {
    if (0.0f > a1) { a2 = a1; c2 = c1; a1 = 0.0f; c1 = 1; }
    else if (0.0f == a1) c1++;
    else if (0.0f > a2) { a2 = 0.0f; c2 = 1; }
    else if (0.0f == a2) c2++;
  }
  return rescan;
}

// ---------- manual grid barrier (device-scope atomics + fences) ----------

__device__ __forceinline__ void gsync(unsigned* cnt) {
  __syncthreads();
  if (threadIdx.x == 0) {
    __threadfence();   // release: publish this block's prior global writes
    __hip_atomic_fetch_add(cnt, 1u, __ATOMIC_RELEASE, __HIP_MEMORY_SCOPE_AGENT);
    while (__hip_atomic_load(cnt, __ATOMIC_ACQUIRE, __HIP_MEMORY_SCOPE_AGENT) < (unsigned)GRID)
      __builtin_amdgcn_s_sleep(16);
    __threadfence();   // acquire: see all blocks' writes
  }
  __syncthreads();
}

// ---------- the fused kernel ----------

union Sh {
  struct {
    unsigned long long skey[1024];
    unsigned long long spay[1024];
    float m0[QN];
    float m1[QN];
    int   asg[NN];
    int   minpos[QN];
    float fst[4];
    int   ist[4];
  } s;                                  // scan phase (block 0)
  struct { float buf[SROWS][NCLS + 1]; } a;   // softmax phase
  struct { float w1[4], w2[4], wb[4]; int wi[4]; } b;  // build reduce
};

__global__ void __launch_bounds__(256, 4)
k_all(const float* __restrict__ logits, const float* __restrict__ pboxes,
      const float* __restrict__ tboxes, const int* __restrict__ tlabels,
      float* __restrict__ mx, float* __restrict__ sm, float* __restrict__ B01,
      unsigned long long* __restrict__ skey_g, int* __restrict__ asg_g,
      unsigned* __restrict__ cnt, int* __restrict__ out) {
#pragma clang fp contract(off)
  __shared__ Sh u;
  const int tid  = threadIdx.x;
  const int lane = tid & 63;
  const int wave = tid >> 6;
  const int blk  = blockIdx.x;

  // ---- Phase A: softmax stats (blocks 0..255, 64 rows each, LDS-staged) ----
  if (blk < 256) {
    int r0 = blk * SROWS;
    const float* src = logits + (size_t)r0 * NCLS;
    for (int i = tid; i < SROWS * NCLS; i += 256) {
      int rr = i / NCLS, cc2 = i - rr * NCLS;
      u.a.buf[rr][cc2] = src[i];
    }
    __syncthreads();
    if (tid < SROWS) {
      const float* row = u.a.buf[tid];
      float m = -INFINITY;
      for (int j = 0; j < NCLS; ++j) m = fmaxf(m, row[j]);
      float s = 0.0f;
      for (int j = 0; j < NCLS; ++j) s += expf(row[j] - m);
      mx[r0 + tid] = m;
      sm[r0 + tid] = s;
    }
  }
  gsync(cnt + 0);

  // ---- Phase B: column build + key (one column per block; B never stored) ----
  {
    int n = blk;
    int lab = tlabels[n];
    float4 tb = ((const float4*)tboxes)[n];
    int rbase = (n / TPI) * QN;
    int q0 = tid, q1 = tid + 256;
    float f0 = build_fx(logits, pboxes, mx, sm, tb, lab, rbase + q0);
    float f1 = build_fx(logits, pboxes, mx, sm, tb, lab, rbase + q1);
    if (n < 2) { B01[n * QN + q0] = f0; B01[n * QN + q1] = f1; }

    float c0 = fminf(f0, 100.0f), c1f = fminf(f1, 100.0f);
    float v1 = fmaxf(c0, c1f), v2 = fminf(c0, c1f);
    float bv; int bi;
    if (f1 > f0) { bv = f1; bi = q1; } else { bv = f0; bi = q0; }
    for (int off = 32; off > 0; off >>= 1) {
      float o1 = __shfl_xor(v1, off), o2 = __shfl_xor(v2, off);
      float ov = __shfl_xor(bv, off); int oi = __shfl_xor(bi, off);
      if (o1 > v1) { v2 = fmaxf(v1, o2); v1 = o1; }
      else v2 = fmaxf(v2, o1);
      if (ov > bv || (ov == bv && oi < bi)) { bv = ov; bi = oi; }
    }
    if (lane == 0) { u.b.w1[wave] = v1; u.b.w2[wave] = v2; u.b.wb[wave] = bv; u.b.wi[wave] = bi; }
    __syncthreads();
    if (tid == 0) {
      float V1 = u.b.w1[0], V2 = u.b.w2[0], BV = u.b.wb[0]; int BI = u.b.wi[0];
      for (int w = 1; w < 4; ++w) {
        float o1 = u.b.w1[w], o2 = u.b.w2[w];
        if (o1 > V1) { V2 = fmaxf(V1, o2); V1 = o1; }
        else V2 = fmaxf(V2, o1);
        float ov = u.b.wb[w]; int oi = u.b.wi[w];
        if (ov > BV || (ov == BV && oi < BI)) { BV = ov; BI = oi; }
      }
      unsigned long long key = 0ull;
      if (n >= 2) {
        unsigned vb = __float_as_uint(V1 - V2);   // ad >= 0: bits monotone
        key = ((unsigned long long)vb << 32) |
              (unsigned long long)(((unsigned)(1023 - n) << 16) | (unsigned)BI);
      }
      skey_g[n] = key;
    }
  }
  gsync(cnt + 1);

  // ---- Phase C: block-0 scan (validated round-7 code, prebuilt keys) ----
  if (blk == 0) {
    unsigned long long* skey = u.s.skey;
    unsigned long long* spay = u.s.spay;
    float* m0 = u.s.m0; float* m1 = u.s.m1;
    int* asg = u.s.asg; int* minpos = u.s.minpos;

    for (int i = tid; i < QN; i += 256) {
      m0[i] = B01[i];
      m1[i] = B01[QN + i];
      minpos[i] = 0x7fffffff;
    }
    for (int i = tid; i < NN; i += 256) { asg[i] = -1; skey[i] = skey_g[i]; }
    for (int i = NN + tid; i < 1024; i += 256) skey[i] = 0ull;
    __syncthreads();

    // bitonic sort (descending), 512 pairs, 2 per thread
    for (int kk2 = 2; kk2 <= 1024; kk2 <<= 1) {
      for (int j = kk2 >> 1; j > 0; j >>= 1) {
#pragma unroll
        for (int k = 0; k < 2; ++k) {
          int g = tid + 256 * k;
          int t = ((g & ~(j - 1)) << 1) | (g & (j - 1));
          int l = t | j;
          unsigned long long a = skey[t], b = skey[l];
          bool sw = ((t & kk2) == 0) ? (a < b) : (a > b);
          if (sw) { skey[t] = b; skey[l] = a; }
        }
        __syncthreads();
      }
    }

    // payload gather (clamped pristine mirrors) + first-touch marking
#pragma unroll
    for (int k = 0; k < 4; ++k) {
      int pp = tid + 256 * k;
      unsigned long long key = skey[pp];
      int r = (int)(key & 0x1FF);
      spay[pp] = (unsigned long long)__float_as_uint(fminf(m0[r], 100.0f)) |
                 ((unsigned long long)__float_as_uint(fminf(m1[r], 100.0f)) << 32);
      if (key != 0ull) atomicMin(&minpos[r], pp);
    }
    __syncthreads();
#pragma unroll
    for (int k = 0; k < 4; ++k) {
      int pp = tid + 256 * k;
      unsigned long long key = skey[pp];
      int r = (int)(key & 0x1FF);
      if (key != 0ull && minpos[r] == pp) skey[pp] |= 0x8000ull;
    }
    if (wave == 0) {
      float A1, A2; int C1, C2;
      wave_maxcount(m0, lane, INFINITY, A1, C1);
      wave_maxcount(m0, lane, A1, A2, C2);
      if (lane == 0) { u.s.fst[0] = A1; u.s.fst[1] = A2; u.s.ist[0] = C1; u.s.ist[1] = C2; }
    } else if (wave == 1) {
      float B1, B2; int D1, D2;
      wave_maxcount(m1, lane, INFINITY, B1, D1);
      wave_maxcount(m1, lane, B1, B2, D2);
      if (lane == 0) { u.s.fst[2] = B1; u.s.fst[3] = B2; u.s.ist[2] = D1; u.s.ist[3] = D2; }
    }
    __syncthreads();

    if (wave == 0) {
      float a1 = u.s.fst[0], a2 = u.s.fst[1], b1 = u.s.fst[2], b2 = u.s.fst[3];
      int   c1 = u.s.ist[0], c2 = u.s.ist[1], d1 = u.s.ist[2], d2 = u.s.ist[3];

      int p = 0, it = 0, w0 = -64;
      float cv = 0.0f, ix0 = 0.0f, ix1 = 0.0f;
      unsigned lo = 0; int row = 0; bool ft = false;
      int negpos0 = -1, negpos1 = -1, dt_m0 = -1, dt_m1 = -1;
      bool trivial0 = false, trivial1 = false;
      int asg0 = -1, asg1 = -1;

      while (it < NN) {
        if (p >= w0 + 64) {                      // reload 64-key window
          w0 = p & ~63;
          unsigned long long kk = skey[w0 + lane];
          unsigned long long yy = spay[w0 + lane];
          cv  = __uint_as_float((unsigned)(kk >> 32));
          lo  = (unsigned)kk;
          row = (int)(lo & 0x1FF);
          ft  = (lo & 0x8000u) != 0;
          ix0 = __uint_as_float((unsigned)yy);
          ix1 = __uint_as_float((unsigned)(yy >> 32));
        }
        float gap0 = (c1 >= 2) ? 0.0f : (a1 - a2);
        float gap1 = (d1 >= 2) ? 0.0f : (b1 - b2);
        float best = fmaxf(gap0, gap1);

        float x0 = trivial0 ? ((row == negpos0) ? -1e-07f : 0.0f)
                            : ((ft && row != dt_m0) ? ix0 : 0.0f);
        float x1 = trivial1 ? ((row == negpos1) ? -1e-07f : 0.0f)
                            : ((ft && row != dt_m1) ? ix1 : 0.0f);
        bool slow = ((!trivial0) && !(a1 > 0.0f && a2 > 0.0f)) ||
                    ((!trivial1) && !(b1 > 0.0f && b2 > 0.0f));
        bool ev = slow ||
                  (trivial0 ? (x0 != 0.0f) : (x0 == a1 || x0 == a2)) ||
                  (trivial1 ? (x1 != 0.0f) : (x1 == b1 || x1 == b2));
        bool sel = !(cv > best);

        int base = p - w0;                       // 0..63
        unsigned long long valid = ~0ull << base;
        unsigned long long selm = __ballot(sel) & valid;
        unsigned long long evm  = __ballot(ev)  & valid;
        int lsel = selm ? (int)__builtin_ctzll(selm) : 64;
        int lev  = evm  ? (int)__builtin_ctzll(evm)  : 64;
        int lmin = (lsel < lev) ? lsel : lev;
        int pref = lmin - base;
        int rem = NN - it;
        if (pref > rem) pref = rem;

        if ((int)lane >= base && (int)lane < base + pref) {   // bulk clean pops
          m0[row] = 0.0f;
          m1[row] = 0.0f;
          asg[1023 - (int)(lo >> 16)] = row;
        }
        p += pref; it += pref;
        if (it >= NN) break;
        if (lmin == 64) continue;                // window exhausted -> reload

        WFENCE();                                // prefix writes visible
        if (lsel <= lev) {
          // ---- selection event: col 0 or col 1 pick ----
          int col = (gap1 > gap0) ? 1 : 0;
          if (col == 0) {
            int rw = trivial0 ? ((negpos0 == 0) ? 1 : 0) : wave_argmax(m0, lane);
            float x1p = m1[rw];
#pragma unroll
            for (int k = 0; k < QN / 64; ++k) m0[lane + 64 * k] = 0.0f;
            if (lane == 0) { m0[rw] = -1e-07f; m1[rw] = 0.0f; }
            WFENCE();
            a1 = 0.0f; c1 = QN - 1; a2 = -1e-07f; c2 = 1;
            trivial0 = true; negpos0 = rw;
            dt_m1 = rw;
            if (negpos1 == rw) negpos1 = -1;
            if (ms_update(x1p, b1, d1, b2, d2)) {
              WFENCE();
              wave_maxcount(m1, lane, INFINITY, b1, d1);
              wave_maxcount(m1, lane, b1, b2, d2);
            }
            asg0 = rw;
            if (asg1 == rw) asg1 = -1;
          } else {
            int rw = trivial1 ? ((negpos1 == 0) ? 1 : 0) : wave_argmax(m1, lane);
            float x0p = m0[rw];
#pragma unroll
            for (int k = 0; k < QN / 64; ++k) m1[lane + 64 * k] = 0.0f;
            if (lane == 0) { m1[rw] = -1e-07f; m0[rw] = 0.0f; }
            WFENCE();
            b1 = 0.0f; d1 = QN - 1; b2 = -1e-07f; d2 = 1;
            trivial1 = true; negpos1 = rw;
            dt_m0 = rw;
            if (negpos0 == rw) negpos0 = -1;
            if (ms_update(x0p, a1, c1, a2, c2)) {
              WFENCE();
              wave_maxcount(m0, lane, INFINITY, a1, c1);
              wave_maxcount(m0, lane, a1, a2, c2);
            }
            asg1 = rw;
            if (asg0 == rw) asg0 = -1;
          }
          ++it;
        } else {
          // ---- multiset event: one scalar pop at lane lmin ----
          float cx0 = __shfl(x0, lmin);
          float cx1 = __shfl(x1, lmin);
          int crow  = __shfl(row, lmin);
          int ccol  = 1023 - __shfl((int)(lo >> 16), lmin);
          if (lane == 0) { m0[crow] = 0.0f; m1[crow] = 0.0f; asg[ccol] = crow; }
          if (negpos0 == crow) negpos0 = -1;
          if (negpos1 == crow) negpos1 = -1;
          if (ms_update(cx0, a1, c1, a2, c2)) {
            WFENCE();
            wave_maxcount(m0, lane, INFINITY, a1, c1);
            wave_maxcount(m0, lane, a1, a2, c2);
          }
          if (ms_update(cx1, b1, d1, b2, d2)) {
            WFENCE();
            wave_maxcount(m1, lane, INFINITY, b1, d1);
            wave_maxcount(m1, lane, b1, b2, d2);
          }
          if (asg0 == crow) asg0 = -1;
          if (asg1 == crow) asg1 = -1;
          ++p; ++it;
        }
      }

      if (lane == 0) { asg[0] = asg0; asg[1] = asg1; }
      WFENCE();
#pragma unroll
      for (int k = 0; k < NN / 64; ++k) {
        int i = lane + 64 * k;
        asg_g[i] = asg[i];
      }
    }
    // waves 1-3 of block 0 fall through and wait at gsync below
  }
  gsync(cnt + 2);

  // ---- Phase D: emit boolean as INT32 0/1, row-major [Q][N] ----
  {
    int t0 = blk * 512 + tid;
#pragma unroll
    for (int k = 0; k < 2; ++k) {
      int t = t0 + k * 256;
      int q = t / NN;
      int n2 = t - q * NN;
      out[t] = (asg_g[n2] == q) ? 1 : 0;
    }
  }
}

extern "C" void kernel_launch(void* const* d_in, const int* in_sizes, int n_in,
                              void* d_out, int out_size, void* d_ws, size_t ws_size,
                              hipStream_t stream) {
  const float* logits  = (const float*)d_in[0];  // [32,512,92]
  const float* pboxes  = (const float*)d_in[1];  // [32,512,4]
  const float* tboxes  = (const float*)d_in[2];  // [768,4]
  const int*   tlabels = (const int*)d_in[3];    // [768]

  float* mx = (float*)d_ws;                         // 16384 f32
  float* sm = mx + BSZ * QN;                        // 16384 f32
  float* B01 = sm + BSZ * QN;                       // 1024 f32 (cols 0,1)
  unsigned long long* skey_g = (unsigned long long*)(B01 + 1024);  // 768 u64
  int* asg_g = (int*)(skey_g + NN);                 // 768 i32
  unsigned* cnt = (unsigned*)(asg_g + NN);          // 3 barrier counters
  int* out = (int*)d_out;

  hipMemsetAsync(cnt, 0, 3 * sizeof(unsigned), stream);
  hipLaunchKernelGGL(k_all, dim3(GRID), dim3(256), 0, stream,
                     logits, pboxes, tboxes, tlabels, mx, sm, B01,
                     skey_g, asg_g, cnt, out);
}

// Round 9
// 63.598 us; speedup vs baseline: 5.9694x; 5.9694x over previous
//
#include <hip/hip_runtime.h>
#include <math.h>

#pragma clang fp contract(off)

#define QN   512   // queries per image
#define NN   768   // total targets (bs*T)
#define BSZ  32    // batch
#define TPI  24    // targets per image
#define NCLS 92    // classes

// single-wave LDS fence: order this wave's ds_writes before its ds_reads
#define WFENCE() asm volatile("s_waitcnt lgkmcnt(0)" ::: "memory")

// ---------- XLA-faithful special functions (verified bit-exact, round 2) ----------

__device__ __forceinline__ float xla_erf_f32(float x) {
#pragma clang fp contract(off)
  float x2 = x * x;
  float p = -2.72614225801306e-10f;
  p = fmaf(x2, p, 2.77068142495902e-08f);
  p = fmaf(x2, p, -2.10102402082508e-06f);
  p = fmaf(x2, p, -5.69250639462346e-05f);
  p = fmaf(x2, p, -7.34990630326855e-04f);
  p = fmaf(x2, p, -2.95459980854025e-03f);
  p = fmaf(x2, p, -1.60960333262415e-02f);
  p = x * p;
  float q = -1.45660718464996e-05f;
  q = fmaf(x2, q, -2.13374055278905e-04f);
  q = fmaf(x2, q, -1.68282697438203e-03f);
  q = fmaf(x2, q, -7.37332916720468e-03f);
  q = fmaf(x2, q, -1.42647390514189e-02f);
  float r = p / q;
  if (fabsf(x) >= 3.832506856900711f) r = copysignf(1.0f, x);
  return r;
}

__device__ __forceinline__ float xla_erfinv_f32(float b) {
#pragma clang fp contract(off)
  float bb = b * b;
  float u = (-bb) + 1.0f;
  float w = -((float)log((double)u));
  float p;
  if (w < 5.0f) {
    float ww = w - 2.5f;
    p = 2.81022636e-08f;
    p = p * ww + 3.43273939e-07f;
    p = p * ww - 3.5233877e-06f;
    p = p * ww - 4.39150654e-06f;
    p = p * ww + 0.00021858087f;
    p = p * ww - 0.00125372503f;
    p = p * ww - 0.00417768164f;
    p = p * ww + 0.246640727f;
    p = p * ww + 1.50140941f;
  } else {
    float ww = (float)sqrt((double)w) - 3.0f;
    p = -0.000200214257f;
    p = p * ww + 0.000100950558f;
    p = p * ww + 0.00134934322f;
    p = p * ww - 0.00367342844f;
    p = p * ww + 0.00573950773f;
    p = p * ww - 0.0076224613f;
    p = p * ww + 0.00943887047f;
    p = p * ww + 1.00167406f;
    p = p * ww + 2.83297682f;
  }
  return p * b;
}

// ---------- fx tail (identical algebra to validated build_fx) ----------

__device__ __forceinline__ float fx_rest(float pc, const float* __restrict__ pboxes,
                                         float4 tb, int r) {
#pragma clang fp contract(off)
  float cost_class = -pc;

  float4 pb = ((const float4*)pboxes)[r];

  float cost_bbox = ((fabsf(pb.x - tb.x) + fabsf(pb.y - tb.y)) +
                     fabsf(pb.z - tb.z)) + fabsf(pb.w - tb.w);

  float p0 = pb.x - 0.5f * pb.z;
  float p1 = pb.y - 0.5f * pb.w;
  float p2 = pb.x + 0.5f * pb.z;
  float p3 = pb.y + 0.5f * pb.w;
  float t0 = tb.x - 0.5f * tb.z;
  float t1 = tb.y - 0.5f * tb.w;
  float t2 = tb.x + 0.5f * tb.z;
  float t3 = tb.y + 0.5f * tb.w;

  float area1 = (p2 - p0) * (p3 - p1);
  float area2 = (t2 - t0) * (t3 - t1);
  float ltx = fmaxf(p0, t0), lty = fmaxf(p1, t1);
  float rbx = fminf(p2, t2), rby = fminf(p3, t3);
  float whx = fmaxf(rbx - ltx, 0.0f), why = fmaxf(rby - lty, 0.0f);
  float inter = whx * why;
  float uni = (area1 + area2) - inter;
  float iou = inter / uni;
  float l2x = fminf(p0, t0), l2y = fminf(p1, t1);
  float r2x = fmaxf(p2, t2), r2y = fmaxf(p3, t3);
  float w2x = fmaxf(r2x - l2x, 0.0f), w2y = fmaxf(r2y - l2y, 0.0f);
  float area = w2x * w2y;
  float giou = iou - (area - uni) / area;

  float C = (cost_bbox + cost_class) + (-giou);

  float z = (-C + 5.5f) / 3.5355339059327378f;
  float prob = 0.5f * (1.0f + xla_erf_f32(z));
  return 0.4242640687119285f * xla_erfinv_f32(prob);
}

// ---------- Stage 1: fused softmax + column build + key (one column/block) ----------
// Per thread: softmax stats for its 2 query rows computed inline (identical
// sequential fmax / expf-sum order -> identical bits), then fx, then the
// round-8-validated block reduce to an 8-byte sorted key. B is never stored;
// only blocks 0,1 spill their columns for the scan mirrors.

__global__ void __launch_bounds__(256) k_buildkey(const float* __restrict__ logits,
                                                  const float* __restrict__ pboxes,
                                                  const float* __restrict__ tboxes,
                                                  const int* __restrict__ tlabels,
                                                  float* __restrict__ B01,
                                                  unsigned long long* __restrict__ skey_g) {
#pragma clang fp contract(off)
  __shared__ float w1s[4], w2s[4], wbs[4];
  __shared__ int   wis[4];
  const int n = blockIdx.x;
  const int tid = threadIdx.x, lane = tid & 63, wave = tid >> 6;
  const int lab = tlabels[n];
  const float4 tb = ((const float4*)tboxes)[n];
  const int rbase = (n / TPI) * QN;

  float f[2];
#pragma unroll
  for (int k = 0; k < 2; ++k) {
    int q = tid + 256 * k;
    int r = rbase + q;
    const float4* row4 = (const float4*)(logits + (size_t)r * NCLS);  // 92 = 23*4, 16B-aligned
    float m = -INFINITY;
#pragma unroll
    for (int j = 0; j < NCLS / 4; ++j) {
      float4 v = row4[j];
      m = fmaxf(m, v.x); m = fmaxf(m, v.y); m = fmaxf(m, v.z); m = fmaxf(m, v.w);
    }
    float s = 0.0f;
#pragma unroll
    for (int j = 0; j < NCLS / 4; ++j) {
      float4 v = row4[j];
      s += expf(v.x - m); s += expf(v.y - m); s += expf(v.z - m); s += expf(v.w - m);
    }
    float gl = logits[(size_t)r * NCLS + lab];
    float pc = expf(gl - m) / s;
    f[k] = fx_rest(pc, pboxes, tb, r);
    if (n < 2) B01[n * QN + q] = f[k];
  }

  // block reduce: clamped top-2 gap + raw argmax (first index on ties)
  float c0 = fminf(f[0], 100.0f), c1f = fminf(f[1], 100.0f);
  float v1 = fmaxf(c0, c1f), v2 = fminf(c0, c1f);
  float bv; int bi;
  if (f[1] > f[0]) { bv = f[1]; bi = tid + 256; } else { bv = f[0]; bi = tid; }
  for (int off = 32; off > 0; off >>= 1) {
    float o1 = __shfl_xor(v1, off), o2 = __shfl_xor(v2, off);
    float ov = __shfl_xor(bv, off); int oi = __shfl_xor(bi, off);
    if (o1 > v1) { v2 = fmaxf(v1, o2); v1 = o1; }
    else v2 = fmaxf(v2, o1);
    if (ov > bv || (ov == bv && oi < bi)) { bv = ov; bi = oi; }
  }
  if (lane == 0) { w1s[wave] = v1; w2s[wave] = v2; wbs[wave] = bv; wis[wave] = bi; }
  __syncthreads();
  if (tid == 0) {
    float V1 = w1s[0], V2 = w2s[0], BV = wbs[0]; int BI = wis[0];
    for (int w = 1; w < 4; ++w) {
      float o1 = w1s[w], o2 = w2s[w];
      if (o1 > V1) { V2 = fmaxf(V1, o2); V1 = o1; }
      else V2 = fmaxf(V2, o1);
      float ov = wbs[w]; int oi = wis[w];
      if (ov > BV || (ov == BV && oi < BI)) { BV = ov; BI = oi; }
    }
    unsigned long long key = 0ull;
    if (n >= 2) {
      unsigned vb = __float_as_uint(V1 - V2);   // gap >= 0: bits monotone
      key = ((unsigned long long)vb << 32) |
            (unsigned long long)(((unsigned)(1023 - n) << 16) | (unsigned)BI);
    }
    skey_g[n] = key;
  }
}

// ---------- scan helpers (validated rounds 3-7) ----------

__device__ __forceinline__ void wave_maxcount(const float* arr, int lane, float bound,
                                              float& mxv, int& cnt) {
  float m = -INFINITY; int c = 0;
#pragma unroll
  for (int k = 0; k < QN / 64; ++k) {
    float v = fminf(arr[lane + 64 * k], 100.0f);
    if (v < bound) {
      if (v > m) { m = v; c = 1; }
      else if (v == m) c++;
    }
  }
  for (int off = 32; off > 0; off >>= 1) {
    float om = __shfl_xor(m, off);
    int oc = __shfl_xor(c, off);
    if (om > m) { m = om; c = oc; }
    else if (om == m) c += oc;
  }
  mxv = m; cnt = c;
}

__device__ __forceinline__ int wave_argmax(const float* arr, int lane) {
  float bv = -INFINITY; int bi = 0x7fffffff;
#pragma unroll
  for (int k = 0; k < QN / 64; ++k) {
    float v = arr[lane + 64 * k];
    if (v > bv) { bv = v; bi = lane + 64 * k; }
  }
  for (int off = 32; off > 0; off >>= 1) {
    float ov = __shfl_xor(bv, off);
    int oi = __shfl_xor(bi, off);
    if (ov > bv || (ov == bv && oi < bi)) { bv = ov; bi = oi; }
  }
  return bi;
}

__device__ __forceinline__ bool ms_update(float x, float& a1, int& c1, float& a2, int& c2) {
  x = fminf(x, 100.0f);
  bool rescan = false;
  if (x == a1) {
    if (--c1 == 0) rescan = true;
  } else if (x == a2) {
    if (--c2 == 0) rescan = true;
  }
  if (!rescan) {
    if (0.0f > a1) { a2 = a1; c2 = c1; a1 = 0.0f; c1 = 1; }
    else if (0.0f == a1) c1++;
    else if (0.0f > a2) { a2 = 0.0f; c2 = 1; }
    else if (0.0f == a2) c2++;
  }
  return rescan;
}

// ---------- Stage 2: 256-thread setup (4-wave sort) + 1-wave windowed scan ----------
// Round-7 validated code; keys are prebuilt by k_buildkey (round-8 validated).

__global__ void __launch_bounds__(256) k_scan(const float* __restrict__ B01,
                                              const unsigned long long* __restrict__ skey_g,
                                              int* __restrict__ asg_out) {
  __shared__ unsigned long long skey[1024];
  __shared__ unsigned long long spay[1024];
  __shared__ float m0[QN];
  __shared__ float m1[QN];
  __shared__ int   asg[NN];
  __shared__ int   minpos[QN];
  __shared__ float fst[4];
  __shared__ int   ist[4];
  const int tid  = threadIdx.x;
  const int lane = tid & 63;
  const int wave = tid >> 6;

  for (int i = tid; i < QN; i += 256) {
    m0[i] = B01[i];
    m1[i] = B01[QN + i];
    minpos[i] = 0x7fffffff;
  }
  for (int i = tid; i < NN; i += 256) { asg[i] = -1; skey[i] = skey_g[i]; }
  for (int i = NN + tid; i < 1024; i += 256) skey[i] = 0ull;
  __syncthreads();

  // bitonic sort (descending), 512 pairs, 2 per thread, 4 waves
  for (int kk2 = 2; kk2 <= 1024; kk2 <<= 1) {
    for (int j = kk2 >> 1; j > 0; j >>= 1) {
#pragma unroll
      for (int k = 0; k < 2; ++k) {
        int g = tid + 256 * k;
        int t = ((g & ~(j - 1)) << 1) | (g & (j - 1));
        int l = t | j;
        unsigned long long a = skey[t], b = skey[l];
        bool sw = ((t & kk2) == 0) ? (a < b) : (a > b);
        if (sw) { skey[t] = b; skey[l] = a; }
      }
      __syncthreads();
    }
  }

  // payload gather (clamped pristine mirrors) + first-touch marking
#pragma unroll
  for (int k = 0; k < 4; ++k) {
    int pp = tid + 256 * k;
    unsigned long long key = skey[pp];
    int r = (int)(key & 0x1FF);
    spay[pp] = (unsigned long long)__float_as_uint(fminf(m0[r], 100.0f)) |
               ((unsigned long long)__float_as_uint(fminf(m1[r], 100.0f)) << 32);
    if (key != 0ull) atomicMin(&minpos[r], pp);
  }
  __syncthreads();
#pragma unroll
  for (int k = 0; k < 4; ++k) {
    int pp = tid + 256 * k;
    unsigned long long key = skey[pp];
    int r = (int)(key & 0x1FF);
    if (key != 0ull && minpos[r] == pp) skey[pp] |= 0x8000ull;
  }
  if (wave == 0) {
    float A1, A2; int C1, C2;
    wave_maxcount(m0, lane, INFINITY, A1, C1);
    wave_maxcount(m0, lane, A1, A2, C2);
    if (lane == 0) { fst[0] = A1; fst[1] = A2; ist[0] = C1; ist[1] = C2; }
  } else if (wave == 1) {
    float B1, B2; int D1, D2;
    wave_maxcount(m1, lane, INFINITY, B1, D1);
    wave_maxcount(m1, lane, B1, B2, D2);
    if (lane == 0) { fst[2] = B1; fst[3] = B2; ist[2] = D1; ist[3] = D2; }
  }
  __syncthreads();
  if (wave != 0) return;          // no barriers past this point

  float a1 = fst[0], a2 = fst[1], b1 = fst[2], b2 = fst[3];
  int   c1 = ist[0], c2 = ist[1], d1 = ist[2], d2 = ist[3];

  int p = 0, it = 0, w0 = -64;
  float cv = 0.0f, ix0 = 0.0f, ix1 = 0.0f;
  unsigned lo = 0; int row = 0; bool ft = false;
  int negpos0 = -1, negpos1 = -1, dt_m0 = -1, dt_m1 = -1;
  bool trivial0 = false, trivial1 = false;
  int asg0 = -1, asg1 = -1;

  while (it < NN) {
    if (p >= w0 + 64) {                      // reload 64-key window
      w0 = p & ~63;
      unsigned long long kk = skey[w0 + lane];
      unsigned long long yy = spay[w0 + lane];
      cv  = __uint_as_float((unsigned)(kk >> 32));
      lo  = (unsigned)kk;
      row = (int)(lo & 0x1FF);
      ft  = (lo & 0x8000u) != 0;
      ix0 = __uint_as_float((unsigned)yy);
      ix1 = __uint_as_float((unsigned)(yy >> 32));
    }
    float gap0 = (c1 >= 2) ? 0.0f : (a1 - a2);
    float gap1 = (d1 >= 2) ? 0.0f : (b1 - b2);
    float best = fmaxf(gap0, gap1);

    float x0 = trivial0 ? ((row == negpos0) ? -1e-07f : 0.0f)
                        : ((ft && row != dt_m0) ? ix0 : 0.0f);
    float x1 = trivial1 ? ((row == negpos1) ? -1e-07f : 0.0f)
                        : ((ft && row != dt_m1) ? ix1 : 0.0f);
    bool slow = ((!trivial0) && !(a1 > 0.0f && a2 > 0.0f)) ||
                ((!trivial1) && !(b1 > 0.0f && b2 > 0.0f));
    bool ev = slow ||
              (trivial0 ? (x0 != 0.0f) : (x0 == a1 || x0 == a2)) ||
              (trivial1 ? (x1 != 0.0f) : (x1 == b1 || x1 == b2));
    bool sel = !(cv > best);

    int base = p - w0;                       // 0..63
    unsigned long long valid = ~0ull << base;
    unsigned long long selm = __ballot(sel) & valid;
    unsigned long long evm  = __ballot(ev)  & valid;
    int lsel = selm ? (int)__builtin_ctzll(selm) : 64;
    int lev  = evm  ? (int)__builtin_ctzll(evm)  : 64;
    int lmin = (lsel < lev) ? lsel : lev;
    int pref = lmin - base;
    int rem = NN - it;
    if (pref > rem) pref = rem;

    if ((int)lane >= base && (int)lane < base + pref) {   // bulk clean pops
      m0[row] = 0.0f;
      m1[row] = 0.0f;
      asg[1023 - (int)(lo >> 16)] = row;
    }
    p += pref; it += pref;
    if (it >= NN) break;
    if (lmin == 64) continue;                // window exhausted -> reload

    WFENCE();                                // prefix writes visible
    if (lsel <= lev) {
      // ---- selection event: col 0 or col 1 pick ----
      int col = (gap1 > gap0) ? 1 : 0;
      if (col == 0) {
        int rw = trivial0 ? ((negpos0 == 0) ? 1 : 0) : wave_argmax(m0, lane);
        float x1p = m1[rw];
#pragma unroll
        for (int k = 0; k < QN / 64; ++k) m0[lane + 64 * k] = 0.0f;
        if (lane == 0) { m0[rw] = -1e-07f; m1[rw] = 0.0f; }
        WFENCE();
        a1 = 0.0f; c1 = QN - 1; a2 = -1e-07f; c2 = 1;
        trivial0 = true; negpos0 = rw;
        dt_m1 = rw;
        if (negpos1 == rw) negpos1 = -1;
        if (ms_update(x1p, b1, d1, b2, d2)) {
          WFENCE();
          wave_maxcount(m1, lane, INFINITY, b1, d1);
          wave_maxcount(m1, lane, b1, b2, d2);
        }
        asg0 = rw;
        if (asg1 == rw) asg1 = -1;
      } else {
        int rw = trivial1 ? ((negpos1 == 0) ? 1 : 0) : wave_argmax(m1, lane);
        float x0p = m0[rw];
#pragma unroll
        for (int k = 0; k < QN / 64; ++k) m1[lane + 64 * k] = 0.0f;
        if (lane == 0) { m1[rw] = -1e-07f; m0[rw] = 0.0f; }
        WFENCE();
        b1 = 0.0f; d1 = QN - 1; b2 = -1e-07f; d2 = 1;
        trivial1 = true; negpos1 = rw;
        dt_m0 = rw;
        if (negpos0 == rw) negpos0 = -1;
        if (ms_update(x0p, a1, c1, a2, c2)) {
          WFENCE();
          wave_maxcount(m0, lane, INFINITY, a1, c1);
          wave_maxcount(m0, lane, a1, a2, c2);
        }
        asg1 = rw;
        if (asg0 == rw) asg0 = -1;
      }
      ++it;
    } else {
      // ---- multiset event: one scalar pop at lane lmin ----
      float cx0 = __shfl(x0, lmin);
      float cx1 = __shfl(x1, lmin);
      int crow  = __shfl(row, lmin);
      int ccol  = 1023 - __shfl((int)(lo >> 16), lmin);
      if (lane == 0) { m0[crow] = 0.0f; m1[crow] = 0.0f; asg[ccol] = crow; }
      if (negpos0 == crow) negpos0 = -1;
      if (negpos1 == crow) negpos1 = -1;
      if (ms_update(cx0, a1, c1, a2, c2)) {
        WFENCE();
        wave_maxcount(m0, lane, INFINITY, a1, c1);
        wave_maxcount(m0, lane, a1, a2, c2);
      }
      if (ms_update(cx1, b1, d1, b2, d2)) {
        WFENCE();
        wave_maxcount(m1, lane, INFINITY, b1, d1);
        wave_maxcount(m1, lane, b1, b2, d2);
      }
      if (asg0 == crow) asg0 = -1;
      if (asg1 == crow) asg1 = -1;
      ++p; ++it;
    }
  }

  if (lane == 0) { asg[0] = asg0; asg[1] = asg1; }
  WFENCE();
#pragma unroll
  for (int k = 0; k < NN / 64; ++k) {
    int i = lane + 64 * k;
    asg_out[i] = asg[i];
  }
}

// ---------- Stage 3: emit boolean as INT32 0/1, row-major [Q][N] ----------

__global__ void k_out(const int* __restrict__ asg, int* __restrict__ out, int total) {
  int t = blockIdx.x * blockDim.x + threadIdx.x;
  if (t >= total) return;
  int q = t / NN;
  int n = t - q * NN;
  out[t] = (asg[n] == q) ? 1 : 0;
}

extern "C" void kernel_launch(void* const* d_in, const int* in_sizes, int n_in,
                              void* d_out, int out_size, void* d_ws, size_t ws_size,
                              hipStream_t stream) {
  const float* logits  = (const float*)d_in[0];  // [32,512,92]
  const float* pboxes  = (const float*)d_in[1];  // [32,512,4]
  const float* tboxes  = (const float*)d_in[2];  // [768,4]
  const int*   tlabels = (const int*)d_in[3];    // [768]

  float* B01 = (float*)d_ws;                                       // 1024 f32
  unsigned long long* skey_g = (unsigned long long*)(B01 + 1024);  // 768 u64 (8B-aligned)
  int* asg_g = (int*)(skey_g + NN);                                // 768 i32
  int* out = (int*)d_out;

  hipLaunchKernelGGL(k_buildkey, dim3(NN), dim3(256), 0, stream,
                     logits, pboxes, tboxes, tlabels, B01, skey_g);
  hipLaunchKernelGGL(k_scan, dim3(1), dim3(256), 0, stream, B01, skey_g, asg_g);
  hipLaunchKernelGGL(k_out, dim3((QN * NN) / 256), dim3(256), 0, stream,
                     asg_g, out, QN * NN);
}

// Round 10
// 49.934 us; speedup vs baseline: 7.6028x; 1.2736x over previous
//
#include <hip/hip_runtime.h>
#include <math.h>

#pragma clang fp contract(off)

#define QN   512   // queries per image
#define NN   768   // total targets (bs*T)
#define BSZ  32    // batch
#define TPI  24    // targets per image
#define NCLS 92    // classes
#define SROWS 64   // softmax rows per block

// single-wave LDS fence: order this wave's ds_writes before its ds_reads
#define WFENCE() asm volatile("s_waitcnt lgkmcnt(0)" ::: "memory")

// ---------- XLA-faithful special functions (verified bit-exact, round 2) ----------

__device__ __forceinline__ float xla_erf_f32(float x) {
#pragma clang fp contract(off)
  float x2 = x * x;
  float p = -2.72614225801306e-10f;
  p = fmaf(x2, p, 2.77068142495902e-08f);
  p = fmaf(x2, p, -2.10102402082508e-06f);
  p = fmaf(x2, p, -5.69250639462346e-05f);
  p = fmaf(x2, p, -7.34990630326855e-04f);
  p = fmaf(x2, p, -2.95459980854025e-03f);
  p = fmaf(x2, p, -1.60960333262415e-02f);
  p = x * p;
  float q = -1.45660718464996e-05f;
  q = fmaf(x2, q, -2.13374055278905e-04f);
  q = fmaf(x2, q, -1.68282697438203e-03f);
  q = fmaf(x2, q, -7.37332916720468e-03f);
  q = fmaf(x2, q, -1.42647390514189e-02f);
  float r = p / q;
  if (fabsf(x) >= 3.832506856900711f) r = copysignf(1.0f, x);
  return r;
}

__device__ __forceinline__ float xla_erfinv_f32(float b) {
#pragma clang fp contract(off)
  float bb = b * b;
  float u = (-bb) + 1.0f;
  float w = -((float)log((double)u));
  float p;
  if (w < 5.0f) {
    float ww = w - 2.5f;
    p = 2.81022636e-08f;
    p = p * ww + 3.43273939e-07f;
    p = p * ww - 3.5233877e-06f;
    p = p * ww - 4.39150654e-06f;
    p = p * ww + 0.00021858087f;
    p = p * ww - 0.00125372503f;
    p = p * ww - 0.00417768164f;
    p = p * ww + 0.246640727f;
    p = p * ww + 1.50140941f;
  } else {
    float ww = (float)sqrt((double)w) - 3.0f;
    p = -0.000200214257f;
    p = p * ww + 0.000100950558f;
    p = p * ww + 0.00134934322f;
    p = p * ww - 0.00367342844f;
    p = p * ww + 0.00573950773f;
    p = p * ww - 0.0076224613f;
    p = p * ww + 0.00943887047f;
    p = p * ww + 1.00167406f;
    p = p * ww + 2.83297682f;
  }
  return p * b;
}

// ---------- Stage 1: softmax stats (round-7 validated; logits read ONCE) ----------

__global__ void __launch_bounds__(256) k_softmax_stats(const float* __restrict__ logits,
                                                       float* __restrict__ mx,
                                                       float* __restrict__ sm) {
#pragma clang fp contract(off)
  __shared__ float buf[SROWS][NCLS + 1];   // +1 pad: conflict-free row reads
  int r0 = blockIdx.x * SROWS;
  const float* src = logits + (size_t)r0 * NCLS;
  for (int i = threadIdx.x; i < SROWS * NCLS; i += 256) {
    int rr = i / NCLS, cc = i - rr * NCLS;
    buf[rr][cc] = src[i];
  }
  __syncthreads();
  int r = threadIdx.x;
  if (r < SROWS) {
    const float* row = buf[r];
    float m = -INFINITY;
    for (int j = 0; j < NCLS; ++j) m = fmaxf(m, row[j]);
    float s = 0.0f;
    for (int j = 0; j < NCLS; ++j) s += expf(row[j] - m);
    mx[r0 + r] = m;
    sm[r0 + r] = s;
  }
}

// ---------- fx tail (identical algebra to validated build_fx) ----------

__device__ __forceinline__ float fx_rest(float pc, const float* __restrict__ pboxes,
                                         float4 tb, int r) {
#pragma clang fp contract(off)
  float cost_class = -pc;

  float4 pb = ((const float4*)pboxes)[r];

  float cost_bbox = ((fabsf(pb.x - tb.x) + fabsf(pb.y - tb.y)) +
                     fabsf(pb.z - tb.z)) + fabsf(pb.w - tb.w);

  float p0 = pb.x - 0.5f * pb.z;
  float p1 = pb.y - 0.5f * pb.w;
  float p2 = pb.x + 0.5f * pb.z;
  float p3 = pb.y + 0.5f * pb.w;
  float t0 = tb.x - 0.5f * tb.z;
  float t1 = tb.y - 0.5f * tb.w;
  float t2 = tb.x + 0.5f * tb.z;
  float t3 = tb.y + 0.5f * tb.w;

  float area1 = (p2 - p0) * (p3 - p1);
  float area2 = (t2 - t0) * (t3 - t1);
  float ltx = fmaxf(p0, t0), lty = fmaxf(p1, t1);
  float rbx = fminf(p2, t2), rby = fminf(p3, t3);
  float whx = fmaxf(rbx - ltx, 0.0f), why = fmaxf(rby - lty, 0.0f);
  float inter = whx * why;
  float uni = (area1 + area2) - inter;
  float iou = inter / uni;
  float l2x = fminf(p0, t0), l2y = fminf(p1, t1);
  float r2x = fmaxf(p2, t2), r2y = fmaxf(p3, t3);
  float w2x = fmaxf(r2x - l2x, 0.0f), w2y = fmaxf(r2y - l2y, 0.0f);
  float area = w2x * w2y;
  float giou = iou - (area - uni) / area;

  float C = (cost_bbox + cost_class) + (-giou);

  float z = (-C + 5.5f) / 3.5355339059327378f;
  float prob = 0.5f * (1.0f + xla_erf_f32(z));
  return 0.4242640687119285f * xla_erfinv_f32(prob);
}

// ---------- Stage 2: column build + key (one column/block; B never stored) ----------
// pc path identical to the round-7 validated k_build (reads mx/sm); reduce
// and key packing identical to the round-8/9 validated k_buildkey.

__global__ void __launch_bounds__(256) k_buildkey(const float* __restrict__ logits,
                                                  const float* __restrict__ pboxes,
                                                  const float* __restrict__ tboxes,
                                                  const int* __restrict__ tlabels,
                                                  const float* __restrict__ mx,
                                                  const float* __restrict__ sm,
                                                  float* __restrict__ B01,
                                                  unsigned long long* __restrict__ skey_g) {
#pragma clang fp contract(off)
  __shared__ float w1s[4], w2s[4], wbs[4];
  __shared__ int   wis[4];
  const int n = blockIdx.x;
  const int tid = threadIdx.x, lane = tid & 63, wave = tid >> 6;
  const int lab = tlabels[n];
  const float4 tb = ((const float4*)tboxes)[n];
  const int rbase = (n / TPI) * QN;

  float f[2];
#pragma unroll
  for (int k = 0; k < 2; ++k) {
    int q = tid + 256 * k;
    int r = rbase + q;
    float pc = expf(logits[(size_t)r * NCLS + lab] - mx[r]) / sm[r];
    f[k] = fx_rest(pc, pboxes, tb, r);
    if (n < 2) B01[n * QN + q] = f[k];
  }

  // block reduce: clamped top-2 gap + raw argmax (first index on ties)
  float c0 = fminf(f[0], 100.0f), c1f = fminf(f[1], 100.0f);
  float v1 = fmaxf(c0, c1f), v2 = fminf(c0, c1f);
  float bv; int bi;
  if (f[1] > f[0]) { bv = f[1]; bi = tid + 256; } else { bv = f[0]; bi = tid; }
  for (int off = 32; off > 0; off >>= 1) {
    float o1 = __shfl_xor(v1, off), o2 = __shfl_xor(v2, off);
    float ov = __shfl_xor(bv, off); int oi = __shfl_xor(bi, off);
    if (o1 > v1) { v2 = fmaxf(v1, o2); v1 = o1; }
    else v2 = fmaxf(v2, o1);
    if (ov > bv || (ov == bv && oi < bi)) { bv = ov; bi = oi; }
  }
  if (lane == 0) { w1s[wave] = v1; w2s[wave] = v2; wbs[wave] = bv; wis[wave] = bi; }
  __syncthreads();
  if (tid == 0) {
    float V1 = w1s[0], V2 = w2s[0], BV = wbs[0]; int BI = wis[0];
    for (int w = 1; w < 4; ++w) {
      float o1 = w1s[w], o2 = w2s[w];
      if (o1 > V1) { V2 = fmaxf(V1, o2); V1 = o1; }
      else V2 = fmaxf(V2, o1);
      float ov = wbs[w]; int oi = wis[w];
      if (ov > BV || (ov == BV && oi < BI)) { BV = ov; BI = oi; }
    }
    unsigned long long key = 0ull;
    if (n >= 2) {
      unsigned vb = __float_as_uint(V1 - V2);   // gap >= 0: bits monotone
      key = ((unsigned long long)vb << 32) |
            (unsigned long long)(((unsigned)(1023 - n) << 16) | (unsigned)BI);
    }
    skey_g[n] = key;
  }
}

// ---------- scan helpers (validated rounds 3-7) ----------

__device__ __forceinline__ void wave_maxcount(const float* arr, int lane, float bound,
                                              float& mxv, int& cnt) {
  float m = -INFINITY; int c = 0;
#pragma unroll
  for (int k = 0; k < QN / 64; ++k) {
    float v = fminf(arr[lane + 64 * k], 100.0f);
    if (v < bound) {
      if (v > m) { m = v; c = 1; }
      else if (v == m) c++;
    }
  }
  for (int off = 32; off > 0; off >>= 1) {
    float om = __shfl_xor(m, off);
    int oc = __shfl_xor(c, off);
    if (om > m) { m = om; c = oc; }
    else if (om == m) c += oc;
  }
  mxv = m; cnt = c;
}

__device__ __forceinline__ int wave_argmax(const float* arr, int lane) {
  float bv = -INFINITY; int bi = 0x7fffffff;
#pragma unroll
  for (int k = 0; k < QN / 64; ++k) {
    float v = arr[lane + 64 * k];
    if (v > bv) { bv = v; bi = lane + 64 * k; }
  }
  for (int off = 32; off > 0; off >>= 1) {
    float ov = __shfl_xor(bv, off);
    int oi = __shfl_xor(bi, off);
    if (ov > bv || (ov == bv && oi < bi)) { bv = ov; bi = oi; }
  }
  return bi;
}

__device__ __forceinline__ bool ms_update(float x, float& a1, int& c1, float& a2, int& c2) {
  x = fminf(x, 100.0f);
  bool rescan = false;
  if (x == a1) {
    if (--c1 == 0) rescan = true;
  } else if (x == a2) {
    if (--c2 == 0) rescan = true;
  }
  if (!rescan) {
    if (0.0f > a1) { a2 = a1; c2 = c1; a1 = 0.0f; c1 = 1; }
    else if (0.0f == a1) c1++;
    else if (0.0f > a2) { a2 = 0.0f; c2 = 1; }
    else if (0.0f == a2) c2++;
  }
  return rescan;
}

// ---------- Stage 3: 512-thread setup (8-wave sort, 1 pair/thread) +
//            1-wave windowed scan (round-7 validated main loop, verbatim) ----------

__global__ void __launch_bounds__(512) k_scan(const float* __restrict__ B01,
                                              const unsigned long long* __restrict__ skey_g,
                                              int* __restrict__ asg_out) {
  __shared__ unsigned long long skey[1024];
  __shared__ unsigned long long spay[1024];
  __shared__ float m0[QN];
  __shared__ float m1[QN];
  __shared__ int   asg[NN];
  __shared__ int   minpos[QN];
  __shared__ float fst[4];
  __shared__ int   ist[4];
  const int tid  = threadIdx.x;
  const int lane = tid & 63;
  const int wave = tid >> 6;

  for (int i = tid; i < QN; i += 512) {
    m0[i] = B01[i];
    m1[i] = B01[QN + i];
    minpos[i] = 0x7fffffff;
  }
  for (int i = tid; i < NN; i += 512) { asg[i] = -1; skey[i] = skey_g[i]; }
  for (int i = NN + tid; i < 1024; i += 512) skey[i] = 0ull;
  __syncthreads();

  // bitonic sort (descending), 512 pairs, 1 per thread, 8 waves
  for (int kk2 = 2; kk2 <= 1024; kk2 <<= 1) {
    for (int j = kk2 >> 1; j > 0; j >>= 1) {
      int g = tid;
      int t = ((g & ~(j - 1)) << 1) | (g & (j - 1));
      int l = t | j;
      unsigned long long a = skey[t], b = skey[l];
      bool sw = ((t & kk2) == 0) ? (a < b) : (a > b);
      if (sw) { skey[t] = b; skey[l] = a; }
      __syncthreads();
    }
  }

  // payload gather (clamped pristine mirrors) + first-touch marking
#pragma unroll
  for (int k = 0; k < 2; ++k) {
    int pp = tid + 512 * k;
    unsigned long long key = skey[pp];
    int r = (int)(key & 0x1FF);
    spay[pp] = (unsigned long long)__float_as_uint(fminf(m0[r], 100.0f)) |
               ((unsigned long long)__float_as_uint(fminf(m1[r], 100.0f)) << 32);
    if (key != 0ull) atomicMin(&minpos[r], pp);
  }
  __syncthreads();
#pragma unroll
  for (int k = 0; k < 2; ++k) {
    int pp = tid + 512 * k;
    unsigned long long key = skey[pp];
    int r = (int)(key & 0x1FF);
    if (key != 0ull && minpos[r] == pp) skey[pp] |= 0x8000ull;
  }
  if (wave == 0) {
    float A1, A2; int C1, C2;
    wave_maxcount(m0, lane, INFINITY, A1, C1);
    wave_maxcount(m0, lane, A1, A2, C2);
    if (lane == 0) { fst[0] = A1; fst[1] = A2; ist[0] = C1; ist[1] = C2; }
  } else if (wave == 1) {
    float B1, B2; int D1, D2;
    wave_maxcount(m1, lane, INFINITY, B1, D1);
    wave_maxcount(m1, lane, B1, B2, D2);
    if (lane == 0) { fst[2] = B1; fst[3] = B2; ist[2] = D1; ist[3] = D2; }
  }
  __syncthreads();
  if (wave != 0) return;          // no barriers past this point

  float a1 = fst[0], a2 = fst[1], b1 = fst[2], b2 = fst[3];
  int   c1 = ist[0], c2 = ist[1], d1 = ist[2], d2 = ist[3];

  int p = 0, it = 0, w0 = -64;
  float cv = 0.0f, ix0 = 0.0f, ix1 = 0.0f;
  unsigned lo = 0; int row = 0; bool ft = false;
  int negpos0 = -1, negpos1 = -1, dt_m0 = -1, dt_m1 = -1;
  bool trivial0 = false, trivial1 = false;
  int asg0 = -1, asg1 = -1;

  while (it < NN) {
    if (p >= w0 + 64) {                      // reload 64-key window
      w0 = p & ~63;
      unsigned long long kk = skey[w0 + lane];
      unsigned long long yy = spay[w0 + lane];
      cv  = __uint_as_float((unsigned)(kk >> 32));
      lo  = (unsigned)kk;
      row = (int)(lo & 0x1FF);
      ft  = (lo & 0x8000u) != 0;
      ix0 = __uint_as_float((unsigned)yy);
      ix1 = __uint_as_float((unsigned)(yy >> 32));
    }
    float gap0 = (c1 >= 2) ? 0.0f : (a1 - a2);
    float gap1 = (d1 >= 2) ? 0.0f : (b1 - b2);
    float best = fmaxf(gap0, gap1);

    float x0 = trivial0 ? ((row == negpos0) ? -1e-07f : 0.0f)
                        : ((ft && row != dt_m0) ? ix0 : 0.0f);
    float x1 = trivial1 ? ((row == negpos1) ? -1e-07f : 0.0f)
                        : ((ft && row != dt_m1) ? ix1 : 0.0f);
    bool slow = ((!trivial0) && !(a1 > 0.0f && a2 > 0.0f)) ||
                ((!trivial1) && !(b1 > 0.0f && b2 > 0.0f));
    bool ev = slow ||
              (trivial0 ? (x0 != 0.0f) : (x0 == a1 || x0 == a2)) ||
              (trivial1 ? (x1 != 0.0f) : (x1 == b1 || x1 == b2));
    bool sel = !(cv > best);

    int base = p - w0;                       // 0..63
    unsigned long long valid = ~0ull << base;
    unsigned long long selm = __ballot(sel) & valid;
    unsigned long long evm  = __ballot(ev)  & valid;
    int lsel = selm ? (int)__builtin_ctzll(selm) : 64;
    int lev  = evm  ? (int)__builtin_ctzll(evm)  : 64;
    int lmin = (lsel < lev) ? lsel : lev;
    int pref = lmin - base;
    int rem = NN - it;
    if (pref > rem) pref = rem;

    if ((int)lane >= base && (int)lane < base + pref) {   // bulk clean pops
      m0[row] = 0.0f;
      m1[row] = 0.0f;
      asg[1023 - (int)(lo >> 16)] = row;
    }
    p += pref; it += pref;
    if (it >= NN) break;
    if (lmin == 64) continue;                // window exhausted -> reload

    WFENCE();                                // prefix writes visible
    if (lsel <= lev) {
      // ---- selection event: col 0 or col 1 pick ----
      int col = (gap1 > gap0) ? 1 : 0;
      if (col == 0) {
        int rw = trivial0 ? ((negpos0 == 0) ? 1 : 0) : wave_argmax(m0, lane);
        float x1p = m1[rw];
#pragma unroll
        for (int k = 0; k < QN / 64; ++k) m0[lane + 64 * k] = 0.0f;
        if (lane == 0) { m0[rw] = -1e-07f; m1[rw] = 0.0f; }
        WFENCE();
        a1 = 0.0f; c1 = QN - 1; a2 = -1e-07f; c2 = 1;
        trivial0 = true; negpos0 = rw;
        dt_m1 = rw;
        if (negpos1 == rw) negpos1 = -1;
        if (ms_update(x1p, b1, d1, b2, d2)) {
          WFENCE();
          wave_maxcount(m1, lane, INFINITY, b1, d1);
          wave_maxcount(m1, lane, b1, b2, d2);
        }
        asg0 = rw;
        if (asg1 == rw) asg1 = -1;
      } else {
        int rw = trivial1 ? ((negpos1 == 0) ? 1 : 0) : wave_argmax(m1, lane);
        float x0p = m0[rw];
#pragma unroll
        for (int k = 0; k < QN / 64; ++k) m1[lane + 64 * k] = 0.0f;
        if (lane == 0) { m1[rw] = -1e-07f; m0[rw] = 0.0f; }
        WFENCE();
        b1 = 0.0f; d1 = QN - 1; b2 = -1e-07f; d2 = 1;
        trivial1 = true; negpos1 = rw;
        dt_m0 = rw;
        if (negpos0 == rw) negpos0 = -1;
        if (ms_update(x0p, a1, c1, a2, c2)) {
          WFENCE();
          wave_maxcount(m0, lane, INFINITY, a1, c1);
          wave_maxcount(m0, lane, a1, a2, c2);
        }
        asg1 = rw;
        if (asg0 == rw) asg0 = -1;
      }
      ++it;
    } else {
      // ---- multiset event: one scalar pop at lane lmin ----
      float cx0 = __shfl(x0, lmin);
      float cx1 = __shfl(x1, lmin);
      int crow  = __shfl(row, lmin);
      int ccol  = 1023 - __shfl((int)(lo >> 16), lmin);
      if (lane == 0) { m0[crow] = 0.0f; m1[crow] = 0.0f; asg[ccol] = crow; }
      if (negpos0 == crow) negpos0 = -1;
      if (negpos1 == crow) negpos1 = -1;
      if (ms_update(cx0, a1, c1, a2, c2)) {
        WFENCE();
        wave_maxcount(m0, lane, INFINITY, a1, c1);
        wave_maxcount(m0, lane, a1, a2, c2);
      }
      if (ms_update(cx1, b1, d1, b2, d2)) {
        WFENCE();
        wave_maxcount(m1, lane, INFINITY, b1, d1);
        wave_maxcount(m1, lane, b1, b2, d2);
      }
      if (asg0 == crow) asg0 = -1;
      if (asg1 == crow) asg1 = -1;
      ++p; ++it;
    }
  }

  if (lane == 0) { asg[0] = asg0; asg[1] = asg1; }
  WFENCE();
#pragma unroll
  for (int k = 0; k < NN / 64; ++k) {
    int i = lane + 64 * k;
    asg_out[i] = asg[i];
  }
}

// ---------- Stage 4: emit boolean as INT32 0/1, row-major [Q][N] ----------

__global__ void k_out(const int* __restrict__ asg, int* __restrict__ out, int total) {
  int t = blockIdx.x * blockDim.x + threadIdx.x;
  if (t >= total) return;
  int q = t / NN;
  int n = t - q * NN;
  out[t] = (asg[n] == q) ? 1 : 0;
}

extern "C" void kernel_launch(void* const* d_in, const int* in_sizes, int n_in,
                              void* d_out, int out_size, void* d_ws, size_t ws_size,
                              hipStream_t stream) {
  const float* logits  = (const float*)d_in[0];  // [32,512,92]
  const float* pboxes  = (const float*)d_in[1];  // [32,512,4]
  const float* tboxes  = (const float*)d_in[2];  // [768,4]
  const int*   tlabels = (const int*)d_in[3];    // [768]

  float* mx = (float*)d_ws;                                        // 16384 f32
  float* sm = mx + BSZ * QN;                                       // 16384 f32
  float* B01 = sm + BSZ * QN;                                      // 1024 f32
  unsigned long long* skey_g = (unsigned long long*)(B01 + 1024);  // 768 u64 (8B-aligned)
  int* asg_g = (int*)(skey_g + NN);                                // 768 i32
  int* out = (int*)d_out;

  hipLaunchKernelGGL(k_softmax_stats, dim3((BSZ * QN) / SROWS), dim3(256), 0, stream,
                     logits, mx, sm);
  hipLaunchKernelGGL(k_buildkey, dim3(NN), dim3(256), 0, stream,
                     logits, pboxes, tboxes, tlabels, mx, sm, B01, skey_g);
  hipLaunchKernelGGL(k_scan, dim3(1), dim3(512), 0, stream, B01, skey_g, asg_g);
  hipLaunchKernelGGL(k_out, dim3((QN * NN) / 256), dim3(256), 0, stream,
                     asg_g, out, QN * NN);
}